// Round 9
// baseline (1240.376 us; speedup 1.0000x reference)
//
#include <hip/hip_runtime.h>

// NodeGNN: h = lrelu(lrelu(x@W1+b1)@W2+b2); 2x GCNConv(16->16) over E=6.4M edges
// + self loops with symmetric norm; out = sum(h@pw+pb, -1). Returns (out[N], h[N,16]).
//
// R13: (a) gather law closed: time = bytes-touched/4 cyc/CU regardless of lane
// scheme/width/residency -> 83us/layer floor; revert to R9's 2-pass 8-lane
// full-table gathers (measured 84/95). (b) The ~250us "rest" is the CSR chain's
// LDS-atomic storms (3 kernels x 6.4M+ LDS atomics). Replace the 5-kernel bucket
// machinery with direct global-atomic construction: degree count (6.4M random 4B
// atomics on L2-resident 800KB ~ 15us), two-level scan (~8us), direct scatter
// csr[atomicAdd(cur[d])]=s (~35us). CSR in-node order becomes nondeterministic:
// sum is order-independent; fp32 reorder noise << bf16 quantization.

#define NEG 0.01f
#define H1S 268                 // h1s row stride (ushorts): cf epilogue writes

typedef __attribute__((ext_vector_type(8))) short short8;
typedef __attribute__((ext_vector_type(4))) float floatx4;
typedef __attribute__((ext_vector_type(2))) float floatx2;
typedef __attribute__((ext_vector_type(4))) unsigned short us4;
typedef __attribute__((ext_vector_type(8))) unsigned short us8;

__device__ __forceinline__ float lrelu(float v) { return v >= 0.0f ? v : NEG * v; }

__device__ __forceinline__ unsigned short f2bf(float f) {
    unsigned int u = __float_as_uint(f);
    u += 0x7fffu + ((u >> 16) & 1u);          // round-to-nearest-even
    return (unsigned short)(u >> 16);
}
__device__ __forceinline__ float bflo(unsigned int u) { return __uint_as_float(u << 16); }
__device__ __forceinline__ float bfhi(unsigned int u) { return __uint_as_float(u & 0xffff0000u); }

// ---------------------------------------------------------------------------
// K-prep: bf16-transposed weights. W1T[n][k] = bf16(W1[k][n]) (256x128),
// W2T[c][k] = bf16(W2[k][c]) (16x256).
// ---------------------------------------------------------------------------
__global__ void prep_kernel(const float* __restrict__ W1, const float* __restrict__ W2,
                            unsigned short* __restrict__ W1T, unsigned short* __restrict__ W2T)
{
    const int idx = blockIdx.x * 256 + threadIdx.x;
    const int stride = gridDim.x * 256;
    for (int i = idx; i < 256 * 128; i += stride) {
        int n = i >> 7, k = i & 127;
        W1T[i] = f2bf(W1[k * 256 + n]);
    }
    for (int i = idx; i < 16 * 256; i += stride) {
        int c = i >> 8, k = i & 255;
        W2T[i] = f2bf(W2[k * 16 + c]);
    }
}

// ---------------------------------------------------------------------------
// K1: MFMA MLP + fused hw1. Block = 256 threads (4 waves), 64 nodes/block.
// (unchanged R12: xbf overlays h1s; epilogue h -> hbuf -> @cw0*dinv -> bf16 rows)
// ---------------------------------------------------------------------------
__global__ __launch_bounds__(256, 4) void mlp_mfma(
    const float* __restrict__ x, const unsigned short* __restrict__ W1T,
    const float* __restrict__ b1, const unsigned short* __restrict__ W2T,
    const float* __restrict__ b2, const float* __restrict__ cw0,
    const float* __restrict__ dinv, unsigned short* __restrict__ hws, int N)
{
    __shared__ unsigned short lds[64 * H1S];   // 34.3 KB (xbf overlays h1s)
    __shared__ float hbuf[64 * 17];            // 4.3 KB
    __shared__ float Wl[256];                  // 1 KB (cw0)
    unsigned short (*xbf)[136] = (unsigned short (*)[136])lds;
    unsigned short (*h1s)[H1S] = (unsigned short (*)[H1S])lds;

    const int tid  = threadIdx.x;
    const int n0   = blockIdx.x * 64;
    const int lane = tid & 63;
    const int lr   = lane & 15;
    const int quad = lane >> 4;
    const int wv   = tid >> 6;

    Wl[tid] = cw0[tid];
    {
        const float4* xg = (const float4*)(x + (size_t)n0 * 128);
#pragma unroll
        for (int i = 0; i < 8; ++i) {
            int f = tid + 256 * i;
            float4 v = xg[f];
            int r = f >> 5, c = (f & 31) * 4;
            us4 p;
            p.x = f2bf(v.x); p.y = f2bf(v.y); p.z = f2bf(v.z); p.w = f2bf(v.w);
            *(us4*)&xbf[r][c] = p;
        }
    }
    __syncthreads();                       // B1: xbf ready

    short8 af[4][4];
#pragma unroll
    for (int m = 0; m < 4; ++m)
#pragma unroll
        for (int kt = 0; kt < 4; ++kt)
            af[m][kt] = *(const short8*)&xbf[m * 16 + lr][kt * 32 + quad * 8];
    __syncthreads();                       // B2: xbf consumed; region free for h1s

    floatx4 acc[4][4];
#pragma unroll
    for (int n = 0; n < 4; ++n)
#pragma unroll
        for (int m = 0; m < 4; ++m)
            acc[n][m] = (floatx4){0.f, 0.f, 0.f, 0.f};

    const int nbase = wv * 64;
#pragma unroll
    for (int n = 0; n < 4; ++n) {
        const unsigned short* bp = &W1T[(size_t)(nbase + n * 16 + lr) * 128 + quad * 8];
        short8 bfr[4];
#pragma unroll
        for (int kt = 0; kt < 4; ++kt) bfr[kt] = *(const short8*)(bp + kt * 32);
#pragma unroll
        for (int kt = 0; kt < 4; ++kt)
#pragma unroll
            for (int m = 0; m < 4; ++m)
                acc[n][m] = __builtin_amdgcn_mfma_f32_16x16x32_bf16(
                    af[m][kt], bfr[kt], acc[n][m], 0, 0, 0);
    }

#pragma unroll
    for (int n = 0; n < 4; ++n) {
        float bc = b1[nbase + n * 16 + lr];
#pragma unroll
        for (int m = 0; m < 4; ++m)
#pragma unroll
            for (int reg = 0; reg < 4; ++reg) {
                float v = lrelu(acc[n][m][reg] + bc);
                h1s[m * 16 + quad * 4 + reg][nbase + n * 16 + lr] = f2bf(v);
            }
    }
    __syncthreads();                       // B3: h1s ready

    floatx4 acc2 = (floatx4){0.f, 0.f, 0.f, 0.f};
#pragma unroll
    for (int kt = 0; kt < 8; ++kt) {
        short8 a2 = *(const short8*)&h1s[wv * 16 + lr][kt * 32 + quad * 8];
        short8 b2f = *(const short8*)&W2T[lr * 256 + kt * 32 + quad * 8];
        acc2 = __builtin_amdgcn_mfma_f32_16x16x32_bf16(a2, b2f, acc2, 0, 0, 0);
    }
    float bb = b2[lr];
#pragma unroll
    for (int reg = 0; reg < 4; ++reg)
        hbuf[(wv * 16 + quad * 4 + reg) * 17 + lr] = lrelu(acc2[reg] + bb);
    __syncthreads();                       // B4: hbuf ready

    // fused hw1: node = tid>>2, features c4..c4+3
    {
        const int node = tid >> 2;
        const int c4   = (tid & 3) * 4;
        float o0 = 0.f, o1 = 0.f, o2 = 0.f, o3 = 0.f;
#pragma unroll
        for (int k = 0; k < 16; ++k) {
            float vk = hbuf[node * 17 + k];
            floatx4 wr = *(const floatx4*)&Wl[k * 16 + c4];
            o0 += vk * wr.x; o1 += vk * wr.y; o2 += vk * wr.z; o3 += vk * wr.w;
        }
        float ds = dinv[n0 + node];
        us4 p;
        p.x = f2bf(o0 * ds); p.y = f2bf(o1 * ds);
        p.z = f2bf(o2 * ds); p.w = f2bf(o3 * ds);
        *(us4*)&hws[(size_t)(n0 + node) * 16 + c4] = p;
    }
}

// ---------------------------------------------------------------------------
// K0: zero the per-node degree counters
// ---------------------------------------------------------------------------
__global__ void zero_cnt(int* __restrict__ cnt, int N)
{
    int i = blockIdx.x * 256 + threadIdx.x;
    if (i < N) cnt[i] = 0;
}

// ---------------------------------------------------------------------------
// K2: per-node degree via global atomics (cnt is 800KB: L2-resident).
// ---------------------------------------------------------------------------
__global__ __launch_bounds__(256) void deg_kernel(
    const int* __restrict__ eidx, int* __restrict__ cnt, int E, int N)
{
    const int stride = gridDim.x * 256;
    for (int e = blockIdx.x * 256 + threadIdx.x; e < E; e += stride) {
        int d = __builtin_nontemporal_load(&eidx[E + e]);
        d = min(max(d, 0), N - 1);
        atomicAdd(&cnt[d], 1);
    }
}

// ---------------------------------------------------------------------------
// K3a: per-block (512 nodes) exclusive scan of cnt -> row_st (local), bsum[b]
// ---------------------------------------------------------------------------
__global__ __launch_bounds__(512) void scan1_kernel(
    const int* __restrict__ cnt, int* __restrict__ row_st, int* __restrict__ bsum, int N)
{
    __shared__ int s[512];
    const int t = threadIdx.x;
    const int node = blockIdx.x * 512 + t;
    int c = (node < N) ? cnt[node] : 0;
    s[t] = c;
    __syncthreads();
#pragma unroll
    for (int o = 1; o < 512; o <<= 1) {
        int v = s[t];
        int u = (t >= o) ? s[t - o] : 0;
        __syncthreads();
        s[t] = v + u;
        __syncthreads();
    }
    if (node < N) row_st[node] = s[t] - c;     // local exclusive
    if (t == 511) bsum[blockIdx.x] = s[511];   // block total
}

// ---------------------------------------------------------------------------
// K3b: single-block exclusive scan of block sums (NB <= 512)
// ---------------------------------------------------------------------------
__global__ __launch_bounds__(512) void scan2_kernel(int* __restrict__ bsum, int NB)
{
    __shared__ int s[512];
    const int t = threadIdx.x;
    int c = (t < NB) ? bsum[t] : 0;
    s[t] = c;
    __syncthreads();
#pragma unroll
    for (int o = 1; o < 512; o <<= 1) {
        int v = s[t];
        int u = (t >= o) ? s[t - o] : 0;
        __syncthreads();
        s[t] = v + u;
        __syncthreads();
    }
    if (t < NB) bsum[t] = s[t] - c;            // exclusive
}

// ---------------------------------------------------------------------------
// K3c: finish: row_st += bsum[block]; cur = row_st; dinv = rsqrt(cnt+1)
// ---------------------------------------------------------------------------
__global__ void finish_kernel(
    const int* __restrict__ cnt, int* __restrict__ row_st, const int* __restrict__ bsum,
    int* __restrict__ cur, float* __restrict__ dinv, int N)
{
    int i = blockIdx.x * 256 + threadIdx.x;
    if (i >= N) return;
    int rs = row_st[i] + bsum[i >> 9];
    row_st[i] = rs;
    cur[i]    = rs;
    dinv[i]   = rsqrtf((float)(cnt[i] + 1));
}

// ---------------------------------------------------------------------------
// K4: direct CSR scatter: csr[atomicAdd(&cur[d],1)] = s. In-node order is
// nondeterministic; the gather sum is order-independent.
// ---------------------------------------------------------------------------
__global__ __launch_bounds__(256) void scatter_kernel(
    const int* __restrict__ eidx, int* __restrict__ cur, int* __restrict__ csr,
    int E, int N)
{
    const int stride = gridDim.x * 256;
    for (int e = blockIdx.x * 256 + threadIdx.x; e < E; e += stride) {
        int s = __builtin_nontemporal_load(&eidx[e]);
        int d = __builtin_nontemporal_load(&eidx[E + e]);
        s = min(max(s, 0), N - 1);
        d = min(max(d, 0), N - 1);
        int pos = atomicAdd(&cur[d], 1);
        __builtin_nontemporal_store(s, &csr[pos]);
    }
}

// ---------------------------------------------------------------------------
// K7a: layer-1 gather fused with layer-2 hw. 8 lanes/node, lane cp owns
// features 2cp,2cp+1 (one uint per edge). Rows pre-scaled by dinv_src.
//   agg = a*dinv_d; v = lrelu(agg + cb0); o = v @ cw1;  row2 = bf16(o*dinv_d)
// 16x16 matmul as an 8-lane shuffle rotation with cw1 in LDS.
// ---------------------------------------------------------------------------
__global__ __launch_bounds__(256) void gather_hw(
    const unsigned short* __restrict__ hws, const float* __restrict__ dinv,
    const int* __restrict__ csr, const int* __restrict__ row_start,
    const int* __restrict__ cnt, const float* __restrict__ cb0,
    const float* __restrict__ cw1, unsigned int* __restrict__ rows2, int N)
{
    __shared__ float Wl[256];
    Wl[threadIdx.x] = cw1[threadIdx.x];
    __syncthreads();

    int t    = blockIdx.x * 256 + threadIdx.x;
    int node = t >> 3;
    int cp   = t & 7;
    if (node >= N) return;

    const unsigned int* rows = (const unsigned int*)hws;   // row i = 8 uints

    int   s0 = row_start[node];
    int   n  = cnt[node];
    float di = dinv[node];
    unsigned int self = rows[(size_t)node * 8 + cp];
    float a0 = bflo(self), a1 = bfhi(self);

    int j = 0;
    for (; j + 8 <= n; j += 8) {
        int s[8];
#pragma unroll
        for (int u = 0; u < 8; ++u) s[u] = __builtin_nontemporal_load(&csr[s0 + j + u]);
        unsigned int v[8];
#pragma unroll
        for (int u = 0; u < 8; ++u) v[u] = rows[(size_t)s[u] * 8 + cp];
#pragma unroll
        for (int u = 0; u < 8; ++u) { a0 += bflo(v[u]); a1 += bfhi(v[u]); }
    }
    for (; j < n; ++j) {
        int s = __builtin_nontemporal_load(&csr[s0 + j]);
        unsigned int v = rows[(size_t)s * 8 + cp];
        a0 += bflo(v); a1 += bfhi(v);
    }

    float v0 = lrelu(a0 * di + cb0[2 * cp]);
    float v1 = lrelu(a1 * di + cb0[2 * cp + 1]);

    float o0 = 0.0f, o1 = 0.0f;
#pragma unroll
    for (int r = 0; r < 8; ++r) {
        int src = (cp + r) & 7;
        float vk0 = __shfl(v0, src, 8);
        float vk1 = __shfl(v1, src, 8);
        floatx2 wa = *(const floatx2*)&Wl[(2 * src) * 16 + 2 * cp];
        floatx2 wb = *(const floatx2*)&Wl[(2 * src + 1) * 16 + 2 * cp];
        o0 += vk0 * wa.x + vk1 * wb.x;
        o1 += vk0 * wa.y + vk1 * wb.y;
    }
    unsigned int u = (unsigned int)f2bf(o0 * di) | ((unsigned int)f2bf(o1 * di) << 16);
    rows2[(size_t)node * 8 + cp] = u;
}

// ---------------------------------------------------------------------------
// K7b: layer-2 gather fused with the final head.
//   v = lrelu(a*dinv_d + cb1);  hout = v;  out = sum(v .* (pw0+pw1)) + pb0+pb1
// ---------------------------------------------------------------------------
__global__ __launch_bounds__(256) void gather_final(
    const unsigned short* __restrict__ hws, const float* __restrict__ dinv,
    const int* __restrict__ csr, const int* __restrict__ row_start,
    const int* __restrict__ cnt, const float* __restrict__ cb1,
    const float* __restrict__ pw, const float* __restrict__ pb,
    float* __restrict__ out, float* __restrict__ hout, int N)
{
    int t    = blockIdx.x * 256 + threadIdx.x;
    int node = t >> 3;
    int cp   = t & 7;
    if (node >= N) return;

    const unsigned int* rows = (const unsigned int*)hws;   // row i = 8 uints

    int   s0 = row_start[node];
    int   n  = cnt[node];
    float di = dinv[node];
    unsigned int self = rows[(size_t)node * 8 + cp];
    float a0 = bflo(self), a1 = bfhi(self);

    int j = 0;
    for (; j + 8 <= n; j += 8) {
        int s[8];
#pragma unroll
        for (int u = 0; u < 8; ++u) s[u] = __builtin_nontemporal_load(&csr[s0 + j + u]);
        unsigned int v[8];
#pragma unroll
        for (int u = 0; u < 8; ++u) v[u] = rows[(size_t)s[u] * 8 + cp];
#pragma unroll
        for (int u = 0; u < 8; ++u) { a0 += bflo(v[u]); a1 += bfhi(v[u]); }
    }
    for (; j < n; ++j) {
        int s = __builtin_nontemporal_load(&csr[s0 + j]);
        unsigned int v = rows[(size_t)s * 8 + cp];
        a0 += bflo(v); a1 += bfhi(v);
    }

    float v0 = lrelu(a0 * di + cb1[2 * cp]);
    float v1 = lrelu(a1 * di + cb1[2 * cp + 1]);

    float s = v0 * (pw[4 * cp] + pw[4 * cp + 1]) + v1 * (pw[4 * cp + 2] + pw[4 * cp + 3]);
    s += __shfl_xor(s, 1, 8);
    s += __shfl_xor(s, 2, 8);
    s += __shfl_xor(s, 4, 8);
    if (cp == 0) out[node] = s + pb[0] + pb[1];

    floatx2 hv; hv.x = v0; hv.y = v1;
    __builtin_nontemporal_store(hv, (floatx2*)&hout[(size_t)node * 16 + 2 * cp]);
}

// ---------------------------------------------------------------------------
extern "C" void kernel_launch(void* const* d_in, const int* in_sizes, int n_in,
                              void* d_out, int out_size, void* d_ws, size_t ws_size,
                              hipStream_t stream)
{
    const float* x   = (const float*)d_in[0];
    const float* W1  = (const float*)d_in[1];
    const float* b1  = (const float*)d_in[2];
    const float* W2  = (const float*)d_in[3];
    const float* b2  = (const float*)d_in[4];
    const float* cw0 = (const float*)d_in[5];
    const float* cb0 = (const float*)d_in[6];
    const float* cw1 = (const float*)d_in[7];
    const float* cb1 = (const float*)d_in[8];
    const float* pw  = (const float*)d_in[9];
    const float* pb  = (const float*)d_in[10];
    const int*   eidx = (const int*)d_in[11];

    const int N  = in_sizes[0] / 128;
    const int E  = in_sizes[11] / 2;
    const int NB = (N + 511) >> 9;            // scan blocks (<= 512 for N <= 262144)

    // workspace carve-out (~60 MB); X region serves rows2
    char* w = (char*)d_ws;
    unsigned short* hws = (unsigned short*)w; w += (size_t)N * 16 * 2;  // bf16 rows (32B)
    float* dinv    = (float*)w; w += (size_t)N * 4;
    int*   cnt     = (int*)w;   w += (size_t)N * 4;
    int*   row_st  = (int*)w;   w += (size_t)N * 4;
    int*   cur     = (int*)w;   w += (size_t)N * 4;
    int*   csr     = (int*)w;   w += (size_t)E * 4;
    char*  X       = w;         w += (size_t)E * 4;
    int*   bsum    = (int*)w;   w += 512 * 4;
    unsigned short* W1T = (unsigned short*)w; w += 256 * 128 * 2;  // 16B-aligned
    unsigned short* W2T = (unsigned short*)w; w += 16 * 256 * 2;

    unsigned int* rows2 = (unsigned int*)X;   // live: gather_hw -> gather_final

    float* out  = (float*)d_out;
    float* hout = out + N;

    const int nb_n = (N + 255) / 256;
    const int nb_g = (N * 8 + 255) / 256;

    // CSR via direct global atomics (L2-resident counters).
    zero_cnt<<<nb_n, 256, 0, stream>>>(cnt, N);
    deg_kernel<<<2048, 256, 0, stream>>>(eidx, cnt, E, N);
    scan1_kernel<<<NB, 512, 0, stream>>>(cnt, row_st, bsum, N);
    scan2_kernel<<<1, 512, 0, stream>>>(bsum, NB);
    finish_kernel<<<nb_n, 256, 0, stream>>>(cnt, row_st, bsum, cur, dinv, N);
    scatter_kernel<<<2048, 256, 0, stream>>>(eidx, cur, csr, E, N);

    prep_kernel<<<32, 256, 0, stream>>>(W1, W2, W1T, W2T);
    mlp_mfma<<<N / 64, 256, 0, stream>>>(x, W1T, b1, W2T, b2, cw0, dinv, hws, N);

    gather_hw<<<nb_g, 256, 0, stream>>>(hws, dinv, csr, row_st, cnt, cb0, cw1, rows2, N);
    gather_final<<<nb_g, 256, 0, stream>>>((const unsigned short*)rows2, dinv, csr, row_st, cnt,
                                           cb1, pw, pb, out, hout, N);
}

// Round 10
// 498.275 us; speedup vs baseline: 2.4893x; 2.4893x over previous
//
#include <hip/hip_runtime.h>

// NodeGNN: h = lrelu(lrelu(x@W1+b1)@W2+b2); 2x GCNConv(16->16) over E=6.4M edges
// + self loops with symmetric norm; out = sum(h@pw+pb, -1). Returns (out[N], h[N,16]).
//
// R14: R13's global-atomic scatter cost 630us (WRITE_SIZE 394MB: every random 4B
// store dirties a 64B sector; write path ~0.7TB/s). Rule: never scatter-write;
// LDS-stage + coalesced flush (R9) is right. This round keeps R9's gathers/MLP
// and restructures the chain: (1) part: chunk-local LDS bucket sort, pairs in
// CHUNK-MAJOR layout (linear flush, no gcur/bucket_count/binary-search), per-chunk
// counts/offsets in ushort Hc/Oc; (2) sumrow+scanb (us-scale) for bucket bases;
// (3) csr: per bucket, pull its segment from each chunk (L2-resident), node-level
// LDS counting sort, coalesced flush. Deletes ~60us bucket_count + scan + search.

#define NEG 0.01f
#define SHIFT 9                 // 512 nodes per bucket
#define BNODES 512
#define PCHUNK 8192             // edges per partition chunk
#define H1S 268                 // h1s row stride (ushorts): cf epilogue writes
#define CSRCAP 19200            // LDS staging for one bucket (mean 16.4K +22sigma)

typedef __attribute__((ext_vector_type(8))) short short8;
typedef __attribute__((ext_vector_type(4))) float floatx4;
typedef __attribute__((ext_vector_type(2))) float floatx2;
typedef __attribute__((ext_vector_type(4))) unsigned short us4;
typedef __attribute__((ext_vector_type(8))) unsigned short us8;

__device__ __forceinline__ float lrelu(float v) { return v >= 0.0f ? v : NEG * v; }

__device__ __forceinline__ unsigned short f2bf(float f) {
    unsigned int u = __float_as_uint(f);
    u += 0x7fffu + ((u >> 16) & 1u);          // round-to-nearest-even
    return (unsigned short)(u >> 16);
}
__device__ __forceinline__ float bflo(unsigned int u) { return __uint_as_float(u << 16); }
__device__ __forceinline__ float bfhi(unsigned int u) { return __uint_as_float(u & 0xffff0000u); }

// ---------------------------------------------------------------------------
// K-prep: bf16-transposed weights. W1T[n][k] = bf16(W1[k][n]) (256x128),
// W2T[c][k] = bf16(W2[k][c]) (16x256).
// ---------------------------------------------------------------------------
__global__ void prep_kernel(const float* __restrict__ W1, const float* __restrict__ W2,
                            unsigned short* __restrict__ W1T, unsigned short* __restrict__ W2T)
{
    const int idx = blockIdx.x * 256 + threadIdx.x;
    const int stride = gridDim.x * 256;
    for (int i = idx; i < 256 * 128; i += stride) {
        int n = i >> 7, k = i & 127;
        W1T[i] = f2bf(W1[k * 256 + n]);
    }
    for (int i = idx; i < 16 * 256; i += stride) {
        int c = i >> 8, k = i & 255;
        W2T[i] = f2bf(W2[k * 16 + c]);
    }
}

// ---------------------------------------------------------------------------
// K1: MFMA MLP + fused hw1. Block = 256 threads (4 waves), 64 nodes/block.
// (unchanged R12: xbf overlays h1s; epilogue h -> hbuf -> @cw0*dinv -> bf16 rows)
// ---------------------------------------------------------------------------
__global__ __launch_bounds__(256, 4) void mlp_mfma(
    const float* __restrict__ x, const unsigned short* __restrict__ W1T,
    const float* __restrict__ b1, const unsigned short* __restrict__ W2T,
    const float* __restrict__ b2, const float* __restrict__ cw0,
    const float* __restrict__ dinv, unsigned short* __restrict__ hws, int N)
{
    __shared__ unsigned short lds[64 * H1S];   // 34.3 KB (xbf overlays h1s)
    __shared__ float hbuf[64 * 17];            // 4.3 KB
    __shared__ float Wl[256];                  // 1 KB (cw0)
    unsigned short (*xbf)[136] = (unsigned short (*)[136])lds;
    unsigned short (*h1s)[H1S] = (unsigned short (*)[H1S])lds;

    const int tid  = threadIdx.x;
    const int n0   = blockIdx.x * 64;
    const int lane = tid & 63;
    const int lr   = lane & 15;
    const int quad = lane >> 4;
    const int wv   = tid >> 6;

    Wl[tid] = cw0[tid];
    {
        const float4* xg = (const float4*)(x + (size_t)n0 * 128);
#pragma unroll
        for (int i = 0; i < 8; ++i) {
            int f = tid + 256 * i;
            float4 v = xg[f];
            int r = f >> 5, c = (f & 31) * 4;
            us4 p;
            p.x = f2bf(v.x); p.y = f2bf(v.y); p.z = f2bf(v.z); p.w = f2bf(v.w);
            *(us4*)&xbf[r][c] = p;
        }
    }
    __syncthreads();                       // B1: xbf ready

    short8 af[4][4];
#pragma unroll
    for (int m = 0; m < 4; ++m)
#pragma unroll
        for (int kt = 0; kt < 4; ++kt)
            af[m][kt] = *(const short8*)&xbf[m * 16 + lr][kt * 32 + quad * 8];
    __syncthreads();                       // B2: xbf consumed; region free for h1s

    floatx4 acc[4][4];
#pragma unroll
    for (int n = 0; n < 4; ++n)
#pragma unroll
        for (int m = 0; m < 4; ++m)
            acc[n][m] = (floatx4){0.f, 0.f, 0.f, 0.f};

    const int nbase = wv * 64;
#pragma unroll
    for (int n = 0; n < 4; ++n) {
        const unsigned short* bp = &W1T[(size_t)(nbase + n * 16 + lr) * 128 + quad * 8];
        short8 bfr[4];
#pragma unroll
        for (int kt = 0; kt < 4; ++kt) bfr[kt] = *(const short8*)(bp + kt * 32);
#pragma unroll
        for (int kt = 0; kt < 4; ++kt)
#pragma unroll
            for (int m = 0; m < 4; ++m)
                acc[n][m] = __builtin_amdgcn_mfma_f32_16x16x32_bf16(
                    af[m][kt], bfr[kt], acc[n][m], 0, 0, 0);
    }

#pragma unroll
    for (int n = 0; n < 4; ++n) {
        float bc = b1[nbase + n * 16 + lr];
#pragma unroll
        for (int m = 0; m < 4; ++m)
#pragma unroll
            for (int reg = 0; reg < 4; ++reg) {
                float v = lrelu(acc[n][m][reg] + bc);
                h1s[m * 16 + quad * 4 + reg][nbase + n * 16 + lr] = f2bf(v);
            }
    }
    __syncthreads();                       // B3: h1s ready

    floatx4 acc2 = (floatx4){0.f, 0.f, 0.f, 0.f};
#pragma unroll
    for (int kt = 0; kt < 8; ++kt) {
        short8 a2 = *(const short8*)&h1s[wv * 16 + lr][kt * 32 + quad * 8];
        short8 b2f = *(const short8*)&W2T[lr * 256 + kt * 32 + quad * 8];
        acc2 = __builtin_amdgcn_mfma_f32_16x16x32_bf16(a2, b2f, acc2, 0, 0, 0);
    }
    float bb = b2[lr];
#pragma unroll
    for (int reg = 0; reg < 4; ++reg)
        hbuf[(wv * 16 + quad * 4 + reg) * 17 + lr] = lrelu(acc2[reg] + bb);
    __syncthreads();                       // B4: hbuf ready

    // fused hw1: node = tid>>2, features c4..c4+3
    {
        const int node = tid >> 2;
        const int c4   = (tid & 3) * 4;
        float o0 = 0.f, o1 = 0.f, o2 = 0.f, o3 = 0.f;
#pragma unroll
        for (int k = 0; k < 16; ++k) {
            float vk = hbuf[node * 17 + k];
            floatx4 wr = *(const floatx4*)&Wl[k * 16 + c4];
            o0 += vk * wr.x; o1 += vk * wr.y; o2 += vk * wr.z; o3 += vk * wr.w;
        }
        float ds = dinv[n0 + node];
        us4 p;
        p.x = f2bf(o0 * ds); p.y = f2bf(o1 * ds);
        p.z = f2bf(o2 * ds); p.w = f2bf(o3 * ds);
        *(us4*)&hws[(size_t)(n0 + node) * 16 + c4] = p;
    }
}

// ---------------------------------------------------------------------------
// K2: chunk-local bucket sort. Each block sorts PCHUNK edges by bucket (d>>9)
// into LDS and flushes LINEARLY to pairs[chunk*PCHUNK + slot] (chunk-major
// layout -> no global coordination). Per-chunk per-bucket count/offset are
// written to Hc/Oc (ushort, chunk-major, coalesced).
// ---------------------------------------------------------------------------
__global__ __launch_bounds__(512) void part_kernel(
    const int* __restrict__ eidx, int* __restrict__ pairs,
    unsigned short* __restrict__ Hc, unsigned short* __restrict__ Oc,
    int E, int N)
{
    __shared__ int hist[BNODES];      // bucket count -> cursor
    __shared__ int sorted[PCHUNK];    // 32KB; doubles as scan scratch
    const int t  = threadIdx.x;
    const int e0 = blockIdx.x * PCHUNK;
    const int elim = min(PCHUNK, E - e0);

    hist[t] = 0;
    __syncthreads();
    for (int i = t; i < elim; i += 512) {
        int d = __builtin_nontemporal_load(&eidx[E + e0 + i]);
        d = min(max(d, 0), N - 1);
        atomicAdd(&hist[d >> SHIFT], 1);
    }
    __syncthreads();

    int c = hist[t];
    sorted[t] = c;
    __syncthreads();
#pragma unroll
    for (int o = 1; o < BNODES; o <<= 1) {
        int v = sorted[t];
        int u = (t >= o) ? sorted[t - o] : 0;
        __syncthreads();
        sorted[t] = v + u;
        __syncthreads();
    }
    const int excl = sorted[t] - c;
    Hc[(size_t)blockIdx.x * 512 + t] = (unsigned short)c;
    Oc[(size_t)blockIdx.x * 512 + t] = (unsigned short)excl;
    hist[t] = excl;                   // becomes local cursor
    __syncthreads();                  // scan-scratch reads done; sorted reusable

    for (int i = t; i < elim; i += 512) {
        int s = __builtin_nontemporal_load(&eidx[e0 + i]);
        int d = __builtin_nontemporal_load(&eidx[E + e0 + i]);
        s = min(max(s, 0), N - 1);
        d = min(max(d, 0), N - 1);
        int b = d >> SHIFT;
        int p = atomicAdd(&hist[b], 1);
        sorted[p] = (s << SHIFT) | (d & (BNODES - 1));
    }
    __syncthreads();

    for (int slot = t; slot < elim; slot += 512)
        pairs[e0 + slot] = sorted[slot];       // linear coalesced flush
}

// ---------------------------------------------------------------------------
// K3a: per-bucket totals: btot[b] = sum_c Hc[c*512+b]
// ---------------------------------------------------------------------------
__global__ __launch_bounds__(256) void sumrow_kernel(
    const unsigned short* __restrict__ Hc, int* __restrict__ btot, int NC)
{
    __shared__ int sb[256];
    const int b = blockIdx.x, t = threadIdx.x;
    int s = 0;
    for (int c = t; c < NC; c += 256) s += Hc[(size_t)c * 512 + b];
    sb[t] = s;
    __syncthreads();
#pragma unroll
    for (int o = 128; o > 0; o >>= 1) {
        if (t < o) sb[t] += sb[t + o];
        __syncthreads();
    }
    if (t == 0) btot[b] = sb[0];
}

// ---------------------------------------------------------------------------
// K3b: single-block exclusive scan of btot -> bbase[0..512]
// ---------------------------------------------------------------------------
__global__ __launch_bounds__(512) void scanb_kernel(
    const int* __restrict__ btot, int* __restrict__ bbase)
{
    __shared__ int s[512];
    const int t = threadIdx.x;
    int c = btot[t];
    s[t] = c;
    __syncthreads();
#pragma unroll
    for (int o = 1; o < 512; o <<= 1) {
        int v = s[t];
        int u = (t >= o) ? s[t - o] : 0;
        __syncthreads();
        s[t] = v + u;
        __syncthreads();
    }
    bbase[t] = s[t] - c;
    if (t == 511) bbase[512] = s[511];
}

// ---------------------------------------------------------------------------
// K4: per-bucket CSR build. Pulls the bucket's segment from each chunk of the
// chunk-major pairs (via Hc/Oc), node-level LDS counting sort, coalesced flush.
// Also writes row_start/cnt/dinv.
// ---------------------------------------------------------------------------
__global__ __launch_bounds__(512) void csr_kernel(
    const int* __restrict__ pairs, const unsigned short* __restrict__ Hc,
    const unsigned short* __restrict__ Oc, const int* __restrict__ bbase,
    int* __restrict__ row_start, int* __restrict__ cnt_out, float* __restrict__ dinv,
    int* __restrict__ csr, int N, int NC)
{
    __shared__ int cnt[BNODES];                  // count -> cursor
    __shared__ int sortedOut[CSRCAP];            // 75KB; first 512 = scan scratch
    const int b = blockIdx.x, t = threadIdx.x;   // 512 threads
    const int base = bbase[b];
    const int mtot = bbase[b + 1] - base;
    const bool fits = (mtot <= CSRCAP);          // statistically always true

    cnt[t] = 0;
    __syncthreads();
    for (int c = t; c < NC; c += 512) {
        int k = Hc[(size_t)c * 512 + b];
        if (k) {
            int g = c * PCHUNK + Oc[(size_t)c * 512 + b];
            for (int j = 0; j < k; ++j) {
                int v = pairs[g + j];
                atomicAdd(&cnt[v & (BNODES - 1)], 1);
            }
        }
    }
    __syncthreads();

    int cc = cnt[t];
    sortedOut[t] = cc;
    __syncthreads();
#pragma unroll
    for (int o = 1; o < BNODES; o <<= 1) {
        int v = sortedOut[t];
        int u = (t >= o) ? sortedOut[t - o] : 0;
        __syncthreads();
        sortedOut[t] = v + u;
        __syncthreads();
    }
    const int excl = sortedOut[t] - cc;
    const int node = (b << SHIFT) + t;
    if (node < N) {
        row_start[node] = base + excl;
        cnt_out[node]   = cc;
        dinv[node]      = rsqrtf((float)(cc + 1));
    }
    cnt[t] = excl;                   // local (0-based) cursor
    __syncthreads();                 // scratch reads done; sortedOut reusable

    for (int c = t; c < NC; c += 512) {
        int k = Hc[(size_t)c * 512 + b];
        if (k) {
            int g = c * PCHUNK + Oc[(size_t)c * 512 + b];
            for (int j = 0; j < k; ++j) {
                int v = pairs[g + j];
                int p = atomicAdd(&cnt[v & (BNODES - 1)], 1);
                int s = v >> SHIFT;
                if (fits) sortedOut[p] = s;
                else      csr[base + p] = s;     // fallback (never statistically)
            }
        }
    }
    __syncthreads();
    if (fits)
        for (int i = t; i < mtot; i += 512)
            csr[base + i] = sortedOut[i];        // coalesced flush
}

// ---------------------------------------------------------------------------
// K7a: layer-1 gather fused with layer-2 hw. 8 lanes/node, lane cp owns
// features 2cp,2cp+1 (one uint per edge). Rows pre-scaled by dinv_src.
//   agg = a*dinv_d; v = lrelu(agg + cb0); o = v @ cw1;  row2 = bf16(o*dinv_d)
// 16x16 matmul as an 8-lane shuffle rotation with cw1 in LDS. (R9-proven)
// ---------------------------------------------------------------------------
__global__ __launch_bounds__(256) void gather_hw(
    const unsigned short* __restrict__ hws, const float* __restrict__ dinv,
    const int* __restrict__ csr, const int* __restrict__ row_start,
    const int* __restrict__ cnt, const float* __restrict__ cb0,
    const float* __restrict__ cw1, unsigned int* __restrict__ rows2, int N)
{
    __shared__ float Wl[256];
    Wl[threadIdx.x] = cw1[threadIdx.x];
    __syncthreads();

    int t    = blockIdx.x * 256 + threadIdx.x;
    int node = t >> 3;
    int cp   = t & 7;
    if (node >= N) return;

    const unsigned int* rows = (const unsigned int*)hws;   // row i = 8 uints

    int   s0 = row_start[node];
    int   n  = cnt[node];
    float di = dinv[node];
    unsigned int self = rows[(size_t)node * 8 + cp];
    float a0 = bflo(self), a1 = bfhi(self);

    int j = 0;
    for (; j + 8 <= n; j += 8) {
        int s[8];
#pragma unroll
        for (int u = 0; u < 8; ++u) s[u] = __builtin_nontemporal_load(&csr[s0 + j + u]);
        unsigned int v[8];
#pragma unroll
        for (int u = 0; u < 8; ++u) v[u] = rows[(size_t)s[u] * 8 + cp];
#pragma unroll
        for (int u = 0; u < 8; ++u) { a0 += bflo(v[u]); a1 += bfhi(v[u]); }
    }
    for (; j < n; ++j) {
        int s = __builtin_nontemporal_load(&csr[s0 + j]);
        unsigned int v = rows[(size_t)s * 8 + cp];
        a0 += bflo(v); a1 += bfhi(v);
    }

    float v0 = lrelu(a0 * di + cb0[2 * cp]);
    float v1 = lrelu(a1 * di + cb0[2 * cp + 1]);

    float o0 = 0.0f, o1 = 0.0f;
#pragma unroll
    for (int r = 0; r < 8; ++r) {
        int src = (cp + r) & 7;
        float vk0 = __shfl(v0, src, 8);
        float vk1 = __shfl(v1, src, 8);
        floatx2 wa = *(const floatx2*)&Wl[(2 * src) * 16 + 2 * cp];
        floatx2 wb = *(const floatx2*)&Wl[(2 * src + 1) * 16 + 2 * cp];
        o0 += vk0 * wa.x + vk1 * wb.x;
        o1 += vk0 * wa.y + vk1 * wb.y;
    }
    unsigned int u = (unsigned int)f2bf(o0 * di) | ((unsigned int)f2bf(o1 * di) << 16);
    rows2[(size_t)node * 8 + cp] = u;
}

// ---------------------------------------------------------------------------
// K7b: layer-2 gather fused with the final head.
//   v = lrelu(a*dinv_d + cb1);  hout = v;  out = sum(v .* (pw0+pw1)) + pb0+pb1
// ---------------------------------------------------------------------------
__global__ __launch_bounds__(256) void gather_final(
    const unsigned short* __restrict__ hws, const float* __restrict__ dinv,
    const int* __restrict__ csr, const int* __restrict__ row_start,
    const int* __restrict__ cnt, const float* __restrict__ cb1,
    const float* __restrict__ pw, const float* __restrict__ pb,
    float* __restrict__ out, float* __restrict__ hout, int N)
{
    int t    = blockIdx.x * 256 + threadIdx.x;
    int node = t >> 3;
    int cp   = t & 7;
    if (node >= N) return;

    const unsigned int* rows = (const unsigned int*)hws;   // row i = 8 uints

    int   s0 = row_start[node];
    int   n  = cnt[node];
    float di = dinv[node];
    unsigned int self = rows[(size_t)node * 8 + cp];
    float a0 = bflo(self), a1 = bfhi(self);

    int j = 0;
    for (; j + 8 <= n; j += 8) {
        int s[8];
#pragma unroll
        for (int u = 0; u < 8; ++u) s[u] = __builtin_nontemporal_load(&csr[s0 + j + u]);
        unsigned int v[8];
#pragma unroll
        for (int u = 0; u < 8; ++u) v[u] = rows[(size_t)s[u] * 8 + cp];
#pragma unroll
        for (int u = 0; u < 8; ++u) { a0 += bflo(v[u]); a1 += bfhi(v[u]); }
    }
    for (; j < n; ++j) {
        int s = __builtin_nontemporal_load(&csr[s0 + j]);
        unsigned int v = rows[(size_t)s * 8 + cp];
        a0 += bflo(v); a1 += bfhi(v);
    }

    float v0 = lrelu(a0 * di + cb1[2 * cp]);
    float v1 = lrelu(a1 * di + cb1[2 * cp + 1]);

    float s = v0 * (pw[4 * cp] + pw[4 * cp + 1]) + v1 * (pw[4 * cp + 2] + pw[4 * cp + 3]);
    s += __shfl_xor(s, 1, 8);
    s += __shfl_xor(s, 2, 8);
    s += __shfl_xor(s, 4, 8);
    if (cp == 0) out[node] = s + pb[0] + pb[1];

    floatx2 hv; hv.x = v0; hv.y = v1;
    __builtin_nontemporal_store(hv, (floatx2*)&hout[(size_t)node * 16 + 2 * cp]);
}

// ---------------------------------------------------------------------------
extern "C" void kernel_launch(void* const* d_in, const int* in_sizes, int n_in,
                              void* d_out, int out_size, void* d_ws, size_t ws_size,
                              hipStream_t stream)
{
    const float* x   = (const float*)d_in[0];
    const float* W1  = (const float*)d_in[1];
    const float* b1  = (const float*)d_in[2];
    const float* W2  = (const float*)d_in[3];
    const float* b2  = (const float*)d_in[4];
    const float* cw0 = (const float*)d_in[5];
    const float* cb0 = (const float*)d_in[6];
    const float* cw1 = (const float*)d_in[7];
    const float* cb1 = (const float*)d_in[8];
    const float* pw  = (const float*)d_in[9];
    const float* pb  = (const float*)d_in[10];
    const int*   eidx = (const int*)d_in[11];

    const int N  = in_sizes[0] / 128;
    const int E  = in_sizes[11] / 2;
    const int NC = (E + PCHUNK - 1) / PCHUNK;     // chunks (782)
    const int B  = (N + BNODES - 1) >> SHIFT;     // buckets (391)

    // workspace carve-out (~62 MB); X region serves pairs -> rows2
    char* w = (char*)d_ws;
    unsigned short* hws = (unsigned short*)w; w += (size_t)N * 16 * 2;  // bf16 rows (32B)
    float* dinv    = (float*)w; w += (size_t)N * 4;
    int*   cnt     = (int*)w;   w += (size_t)N * 4;
    int*   row_st  = (int*)w;   w += (size_t)N * 4;
    int*   csr     = (int*)w;   w += (size_t)E * 4;
    char*  X       = w;         w += (size_t)E * 4;
    unsigned short* Hc = (unsigned short*)w; w += (size_t)NC * 512 * 2; // 0.8MB
    unsigned short* Oc = (unsigned short*)w; w += (size_t)NC * 512 * 2; // 0.8MB
    int*   btot    = (int*)w;   w += 512 * 4;
    int*   bbase   = (int*)w;   w += (512 + 4) * 4;   // +4 keeps 16B alignment below
    unsigned short* W1T = (unsigned short*)w; w += 256 * 128 * 2;  // 16B-aligned
    unsigned short* W2T = (unsigned short*)w; w += 16 * 256 * 2;

    int*          pairs = (int*)X;           // live: part -> csr
    unsigned int* rows2 = (unsigned int*)X;  // live: gather_hw -> gather_final (pairs dead)

    float* out  = (float*)d_out;
    float* hout = out + N;

    const int nb_g = (N * 8 + 255) / 256;

    // CSR chain (all writes coalesced; chunk-major pairs, no global run bases).
    part_kernel<<<NC, 512, 0, stream>>>(eidx, pairs, Hc, Oc, E, N);
    sumrow_kernel<<<512, 256, 0, stream>>>(Hc, btot, NC);
    scanb_kernel<<<1, 512, 0, stream>>>(btot, bbase);
    csr_kernel<<<B, 512, 0, stream>>>(pairs, Hc, Oc, bbase, row_st, cnt, dinv, csr, N, NC);

    prep_kernel<<<32, 256, 0, stream>>>(W1, W2, W1T, W2T);
    mlp_mfma<<<N / 64, 256, 0, stream>>>(x, W1T, b1, W2T, b2, cw0, dinv, hws, N); // pairs dead

    gather_hw<<<nb_g, 256, 0, stream>>>(hws, dinv, csr, row_st, cnt, cb0, cw1, rows2, N);
    gather_final<<<nb_g, 256, 0, stream>>>((const unsigned short*)rows2, dinv, csr, row_st, cnt,
                                           cb1, pw, pb, out, hout, N);
}